// Round 1
// baseline (582.185 us; speedup 1.0000x reference)
//
#include <hip/hip_runtime.h>
#include <hip/hip_bf16.h>

#define NUM_REAL 19
#define NIMG     4
#define T_TOT    76        // NIMG*NUM_REAL
#define V_SEL    131       // 10000 / 76
#define M_ROWS   9956      // T_TOT*V_SEL
#define MP       9984      // padded to 78*128
#define CDIM     256
#define P_PIX    65536
#define NPOS     524       // NIMG*V_SEL (same-class rows incl. self)
#define TILE     128
#define BK       32
#define LDSP     40        // padded LDS pitch (bf16 elems)

typedef __attribute__((ext_vector_type(8))) short short8;
typedef __attribute__((ext_vector_type(4))) float floatx4;

// ---------------- Kernel 1: per-(image,class) first-V pixel selection ----------------
__global__ __launch_bounds__(512) void k_select(const int* __restrict__ label,
                                                int* __restrict__ sel)
{
    __shared__ int cnts[NUM_REAL * 512];
    const int n   = blockIdx.x;
    const int tid = threadIdx.x;
    for (int k = 0; k < NUM_REAL; ++k) cnts[k * 512 + tid] = 0;
    __syncthreads();
    const int* lab = label + n * 1048576;   // [1024][1024]
    const int p0 = tid * 128;               // 128 dom-pixels per thread, in order
    for (int j = 0; j < 128; ++j) {
        int p = p0 + j;
        int c = lab[((p >> 8) << 12) + ((p & 255) << 2)];  // label[4*r][4*cc]
        cnts[c * 512 + tid]++;
    }
    __syncthreads();
    if (tid < NUM_REAL) {                   // exclusive scan over 512 chunks
        int run = 0, base = tid * 512;
        for (int t2 = 0; t2 < 512; ++t2) {
            int tmp = cnts[base + t2];
            cnts[base + t2] = run;
            run += tmp;
        }
    }
    __syncthreads();
    bool need = false;
    for (int k = 0; k < NUM_REAL; ++k) if (cnts[k * 512 + tid] < V_SEL) need = true;
    if (need) {
        for (int j = 0; j < 128; ++j) {
            int p = p0 + j;
            int c = lab[((p >> 8) << 12) + ((p & 255) << 2)];
            int r = cnts[c * 512 + tid]++;
            if (r < V_SEL) sel[(n * NUM_REAL + c) * V_SEL + r] = p;
        }
    }
}

// ---------------- Kernel 2: gather + L2-normalize -> bf16 F[MP][256] ----------------
__global__ __launch_bounds__(256) void k_gather(const float* __restrict__ feats,
                                                const int* __restrict__ sel,
                                                unsigned short* __restrict__ F)
{
    const int i = blockIdx.x;          // row 0..MP-1
    const int c = threadIdx.x;         // channel
    __shared__ float red[4];
    float x = 0.f;
    if (i < M_ROWS) {
        int t = i / V_SEL;             // t = b*19 + m
        int b = t / NUM_REAL;
        int p = sel[i];                // sel laid out [t][v] == flat i
        x = feats[(size_t)(b * CDIM + c) * P_PIX + p];
    }
    float ss = x * x;
    #pragma unroll
    for (int s = 32; s > 0; s >>= 1) ss += __shfl_xor(ss, s, 64);
    if ((c & 63) == 0) red[c >> 6] = ss;
    __syncthreads();
    float sum  = red[0] + red[1] + red[2] + red[3];
    float rinv = (sum > 0.f) ? rsqrtf(sum) : 0.f;
    __hip_bfloat16 h = __float2bfloat16(x * rinv);
    F[(size_t)i * CDIM + c] = *reinterpret_cast<unsigned short*>(&h);
}

// ---------------- Kernel 3: bf16 MFMA Gram tiles + fused neg-sum / pos-store ----------------
__global__ __launch_bounds__(256) void k_gemm(const unsigned short* __restrict__ F,
                                              float* __restrict__ negsum,
                                              float* __restrict__ posst)
{
    __shared__ unsigned short As[TILE * LDSP];
    __shared__ unsigned short Bs[TILE * LDSP];
    const int bi = blockIdx.y, bj = blockIdx.x;
    const int i0 = bi * TILE, j0 = bj * TILE;
    const int tid  = threadIdx.x;
    const int wave = tid >> 6, lane = tid & 63;
    const int qr = lane >> 4, lr = lane & 15;
    const int wr = (wave >> 1) * 64, wc = (wave & 1) * 64;

    floatx4 acc[4][4];
    floatx4 zero4 = {0.f, 0.f, 0.f, 0.f};
    #pragma unroll
    for (int a = 0; a < 4; ++a)
        #pragma unroll
        for (int b = 0; b < 4; ++b) acc[a][b] = zero4;

    const int lrow = tid >> 2;   // staging row 0..63 (+64 on rep 1)
    const int loc  = tid & 3;    // which 8-elem chunk of the 32-wide K slab

    for (int kc = 0; kc < CDIM; kc += BK) {
        #pragma unroll
        for (int rep = 0; rep < 2; ++rep) {
            int row = lrow + rep * 64;
            *reinterpret_cast<uint4*>(&As[row * LDSP + loc * 8]) =
                *reinterpret_cast<const uint4*>(F + (size_t)(i0 + row) * CDIM + kc + loc * 8);
            *reinterpret_cast<uint4*>(&Bs[row * LDSP + loc * 8]) =
                *reinterpret_cast<const uint4*>(F + (size_t)(j0 + row) * CDIM + kc + loc * 8);
        }
        __syncthreads();
        short8 a[4], b[4];
        #pragma unroll
        for (int mi = 0; mi < 4; ++mi)
            a[mi] = *reinterpret_cast<const short8*>(&As[(wr + mi * 16 + lr) * LDSP + qr * 8]);
        #pragma unroll
        for (int ni = 0; ni < 4; ++ni)
            b[ni] = *reinterpret_cast<const short8*>(&Bs[(wc + ni * 16 + lr) * LDSP + qr * 8]);
        #pragma unroll
        for (int mi = 0; mi < 4; ++mi)
            #pragma unroll
            for (int ni = 0; ni < 4; ++ni)
                acc[mi][ni] = __builtin_amdgcn_mfma_f32_16x16x32_bf16(a[mi], b[ni], acc[mi][ni], 0, 0, 0);
        __syncthreads();
    }

    // ---- epilogue: logits = 2*G; same-class -> pos_store, diff-class -> exp into negsum ----
    int  jcls[4], jpidx[4];
    bool jval[4];
    #pragma unroll
    for (int ni = 0; ni < 4; ++ni) {
        int gcol = j0 + wc + ni * 16 + lr;
        jval[ni] = gcol < M_ROWS;
        unsigned tj  = (unsigned)gcol / V_SEL;
        unsigned vj  = (unsigned)gcol - tj * V_SEL;
        unsigned bj_ = tj / NUM_REAL;
        jcls[ni]  = (int)(tj - bj_ * NUM_REAL);
        jpidx[ni] = (int)(bj_ * V_SEL + vj);
    }
    #pragma unroll
    for (int mi = 0; mi < 4; ++mi) {
        #pragma unroll
        for (int reg = 0; reg < 4; ++reg) {
            int grow  = i0 + wr + mi * 16 + qr * 4 + reg;  // C/D: row=(lane>>4)*4+reg, col=lane&15
            bool ival = grow < M_ROWS;
            unsigned ti  = (unsigned)grow / V_SEL;
            unsigned bi_ = ti / NUM_REAL;
            int icls = (int)(ti - bi_ * NUM_REAL);
            float negacc = 0.f;
            #pragma unroll
            for (int ni = 0; ni < 4; ++ni) {
                float logit = acc[mi][ni][reg] * 2.0f;     // /TEMPERATURE
                if (ival && jval[ni]) {
                    if (icls == jcls[ni])
                        posst[(size_t)grow * NPOS + jpidx[ni]] = logit;
                    else
                        negacc += __expf(logit);
                }
            }
            negacc += __shfl_xor(negacc, 1, 64);
            negacc += __shfl_xor(negacc, 2, 64);
            negacc += __shfl_xor(negacc, 4, 64);
            negacc += __shfl_xor(negacc, 8, 64);
            if (lr == 0 && ival) atomicAdd(&negsum[grow], negacc);
        }
    }
}

// ---------------- Kernel 4: finalize loss ----------------
__global__ __launch_bounds__(256) void k_finalize(const float* __restrict__ posst,
                                                  const float* __restrict__ negsum,
                                                  float* __restrict__ out)
{
    const float scale = -1.0f / (523.0f * (float)M_ROWS);
    float local = 0.f;
    for (int row = blockIdx.x; row < M_ROWS; row += gridDim.x) {
        float ns = negsum[row];
        unsigned ti = (unsigned)row / V_SEL;
        unsigned vi = (unsigned)row - ti * V_SEL;
        int selfp = (int)((ti / NUM_REAL) * V_SEL + vi);
        for (int j = threadIdx.x; j < NPOS; j += blockDim.x) {
            if (j == selfp) continue;
            float l = posst[(size_t)row * NPOS + j];
            local += l - __logf(__expf(l) + ns);
        }
    }
    #pragma unroll
    for (int s = 32; s > 0; s >>= 1) local += __shfl_xor(local, s, 64);
    __shared__ float red[4];
    if ((threadIdx.x & 63) == 0) red[threadIdx.x >> 6] = local;
    __syncthreads();
    if (threadIdx.x == 0)
        atomicAdd(out, (red[0] + red[1] + red[2] + red[3]) * scale);
}

extern "C" void kernel_launch(void* const* d_in, const int* in_sizes, int n_in,
                              void* d_out, int out_size, void* d_ws, size_t ws_size,
                              hipStream_t stream)
{
    const int*   label = (const int*)d_in[0];
    const float* feats = (const float*)d_in[1];
    float*       out   = (float*)d_out;

    char* ws = (char*)d_ws;
    unsigned short* F = (unsigned short*)ws;                    // MP*CDIM*2 = 5,111,808 B
    size_t off = (size_t)MP * CDIM * 2;
    int* sel = (int*)(ws + off);
    off += (size_t)T_TOT * V_SEL * 4;
    off = (off + 255) & ~(size_t)255;
    float* negsum = (float*)(ws + off);
    off += (size_t)M_ROWS * 4;
    off = (off + 255) & ~(size_t)255;
    float* posst = (float*)(ws + off);                          // M_ROWS*NPOS*4 ≈ 20.9 MB

    hipMemsetAsync(sel, 0, (size_t)T_TOT * V_SEL * 4, stream);
    hipMemsetAsync(negsum, 0, (size_t)M_ROWS * 4, stream);
    hipMemsetAsync(out, 0, sizeof(float), stream);

    k_select<<<NIMG, 512, 0, stream>>>(label, sel);
    k_gather<<<MP, 256, 0, stream>>>(feats, sel, F);
    dim3 g(MP / TILE, MP / TILE);
    k_gemm<<<g, 256, 0, stream>>>(F, negsum, posst);
    k_finalize<<<256, 256, 0, stream>>>(posst, negsum, out);
}